// Round 8
// baseline (722.425 us; speedup 1.0000x reference)
//
#include <hip/hip_runtime.h>

// 3-layer GCN 2->16->16->1, N=250k, E=4M.
// R8: XCD-affinity src partitioning. Edges binned once by (dst_chunk c,
// src_group g), bin id = c*8+g. Layer2's gather runs one block per bin with
// blockIdx%8 == g -> all blocks reading src-slice g land on XCD g (MI355X
// round-robins blocks over 8 XCDs), so each 2MB dh1 slice is served by ONE
// XCD's L2: gathers become L2 hits instead of ~610GB/s random fabric misses.
// Per-bin partial sums accumulate in a 2048x16 LDS tile (139KB, 1 block/CU)
// and flush with coalesced float atomics into global agg; a flat epilogue
// applies W2+b2+relu+W3. Layers 1/3 gather from small L2-resident buffers.
// Transforms commuted around the (linear) aggregation as before.

constexpr int CH   = 2048;   // dst nodes per chunk
constexpr int G    = 256;    // binning blocks
constexpr int F    = 16;
constexpr int BMAX = 1024;   // max bins; NC=123 chunks * 8 groups = 984

// ---- binning by (dst chunk, src group) --------------------------------------

__global__ __launch_bounds__(1024) void k_bcount(const int* __restrict__ src,
        const int* __restrict__ dst, int* __restrict__ bcount,
        int E, int chunk, int npg, int B) {
    __shared__ int h[BMAX];
    for (int k = threadIdx.x; k < B; k += 1024) h[k] = 0;
    __syncthreads();
    int beg = blockIdx.x * chunk, end = min(beg + chunk, E);
    for (int i = beg + threadIdx.x; i < end; i += 1024) {
        int s = __builtin_nontemporal_load(&src[i]);
        int d = __builtin_nontemporal_load(&dst[i]);
        atomicAdd(&h[(d >> 11) * 8 + s / npg], 1);
    }
    __syncthreads();
    for (int k = threadIdx.x; k < B; k += 1024)
        bcount[blockIdx.x * B + k] = h[k];      // block-major, coalesced
}

// Single block: bin totals -> exclusive scan -> per-(block,bin) bases in place.
__global__ __launch_bounds__(1024) void k_scan(int* __restrict__ bcount,
        int* __restrict__ colbase, int E, int B) {
    __shared__ int tot[1024];
    int k = threadIdx.x;
    int s = 0;
    if (k < B) for (int b = 0; b < G; ++b) s += bcount[b * B + k];
    tot[k] = s;
    __syncthreads();
    for (int off = 1; off < 1024; off <<= 1) {
        int t = (k >= off) ? tot[k - off] : 0;
        __syncthreads();
        tot[k] += t;
        __syncthreads();
    }
    if (k < B) {
        int run = tot[k] - s;
        colbase[k] = run;
        for (int b = 0; b < G; ++b) {
            int t = bcount[b * B + k];
            bcount[b * B + k] = run;
            run += t;
        }
    }
    if (k == 0) colbase[B] = E;
}

// ent[pos] = (src_local << 11) | dst_local   (15 + 11 bits; group/chunk from bin)
__global__ __launch_bounds__(1024) void k_bfill(const int* __restrict__ src,
        const int* __restrict__ dst, const int* __restrict__ base,
        int* __restrict__ ent, int E, int chunk, int npg, int B) {
    __shared__ int cur[BMAX];
    for (int k = threadIdx.x; k < B; k += 1024)
        cur[k] = base[blockIdx.x * B + k];
    __syncthreads();
    int beg = blockIdx.x * chunk, end = min(beg + chunk, E);
    for (int i = beg + threadIdx.x; i < end; i += 1024) {
        int s = __builtin_nontemporal_load(&src[i]);
        int d = __builtin_nontemporal_load(&dst[i]);
        int g = s / npg;
        int pos = atomicAdd(&cur[(d >> 11) * 8 + g], 1);
        ent[pos] = ((s - g * npg) << 11) | (d & (CH - 1));
    }
}

// ---- per-chunk degree + pre-scaled 2-wide input ------------------------------

__global__ __launch_bounds__(512) void k_prep(const int* __restrict__ ent,
        const int* __restrict__ colbase, const float* __restrict__ x,
        float* __restrict__ dinv, float* __restrict__ dx, int n) {
    __shared__ int h[CH];
    for (int t = threadIdx.x; t < CH; t += 512) h[t] = 0;
    __syncthreads();
    int beg = colbase[blockIdx.x * 8], end = colbase[blockIdx.x * 8 + 8];
    for (int e = beg + threadIdx.x; e < end; e += 512)
        atomicAdd(&h[ent[e] & (CH - 1)], 1);
    __syncthreads();
    for (int r = threadIdx.x; r < CH; r += 512) {
        int i = blockIdx.x * CH + r;
        if (i < n) {
            float di = rsqrtf((float)h[r] + 1.0f);
            dinv[i] = di;
            float2 xv = reinterpret_cast<const float2*>(x)[i];
            reinterpret_cast<float2*>(dx)[i] = make_float2(di * xv.x, di * xv.y);
        }
    }
}

// ---- layer 1: aggregate 2-wide dx; epilogue (2->16) W1 + b1 + relu ----------
// dh1[i] = dinv[i] * relu( [dinv[i]*(sum dx[src] + dx[i])] @ W1 + b1 )

__global__ __launch_bounds__(512) void k_layer1(const int* __restrict__ ent,
        const int* __restrict__ colbase, const float* __restrict__ dinv,
        const float* __restrict__ dx, const float* __restrict__ W1,
        const float* __restrict__ b1, float* __restrict__ dh1, int n, int npg) {
    __shared__ float acc[CH * 2];
    __shared__ float sW[32];
    __shared__ float sb[16];
    if (threadIdx.x < 32) sW[threadIdx.x] = W1[threadIdx.x];
    if (threadIdx.x >= 32 && threadIdx.x < 48) sb[threadIdx.x - 32] = b1[threadIdx.x - 32];
    for (int t = threadIdx.x; t < CH * 2; t += 512) acc[t] = 0.0f;
    __syncthreads();
    for (int g = 0; g < 8; ++g) {
        int sbase = g * npg;
        int beg = colbase[blockIdx.x * 8 + g], end = colbase[blockIdx.x * 8 + g + 1];
        int e = beg + threadIdx.x;
        for (; e + 512 < end; e += 1024) {
            int v0 = ent[e], v1 = ent[e + 512];
            float2 a0 = reinterpret_cast<const float2*>(dx)[sbase + (v0 >> 11)];
            float2 a1 = reinterpret_cast<const float2*>(dx)[sbase + (v1 >> 11)];
            atomicAdd(&acc[(v0 & (CH - 1)) * 2 + 0], a0.x);
            atomicAdd(&acc[(v0 & (CH - 1)) * 2 + 1], a0.y);
            atomicAdd(&acc[(v1 & (CH - 1)) * 2 + 0], a1.x);
            atomicAdd(&acc[(v1 & (CH - 1)) * 2 + 1], a1.y);
        }
        if (e < end) {
            int v = ent[e];
            float2 a = reinterpret_cast<const float2*>(dx)[sbase + (v >> 11)];
            atomicAdd(&acc[(v & (CH - 1)) * 2 + 0], a.x);
            atomicAdd(&acc[(v & (CH - 1)) * 2 + 1], a.y);
        }
    }
    __syncthreads();
    for (int r = threadIdx.x; r < CH; r += 512) {
        int i = blockIdx.x * CH + r;
        if (i < n) {
            float di = dinv[i];
            float2 ds = reinterpret_cast<const float2*>(dx)[i];
            float a0 = di * (acc[r * 2 + 0] + ds.x);
            float a1 = di * (acc[r * 2 + 1] + ds.y);
            float4* orow = reinterpret_cast<float4*>(dh1 + (size_t)i * F);
#pragma unroll
            for (int q = 0; q < 4; ++q) {
                float4 o;
                o.x = di * fmaxf(a0 * sW[4*q+0] + a1 * sW[16 + 4*q+0] + sb[4*q+0], 0.0f);
                o.y = di * fmaxf(a0 * sW[4*q+1] + a1 * sW[16 + 4*q+1] + sb[4*q+1], 0.0f);
                o.z = di * fmaxf(a0 * sW[4*q+2] + a1 * sW[16 + 4*q+2] + sb[4*q+2], 0.0f);
                o.w = di * fmaxf(a0 * sW[4*q+3] + a1 * sW[16 + 4*q+3] + sb[4*q+3], 0.0f);
                orow[q] = o;
            }
        }
    }
}

// ---- layer 2 pass A: one block per (chunk,group) bin; blockIdx%8 = group ----
// Gathers dh1 rows from the block's 2MB src slice (XCD-L2-resident), sums into
// a 2048x16 LDS tile, flushes with coalesced float atomics into agg.

__global__ __launch_bounds__(512) void k_layer2a(const int* __restrict__ ent,
        const int* __restrict__ colbase, const float* __restrict__ dh1,
        float* __restrict__ agg, int npg) {
    __shared__ float acc[CH * 17];       // stride 17: bank-spread
    for (int t = threadIdx.x; t < CH * 17; t += 512) acc[t] = 0.0f;
    __syncthreads();
    int g = blockIdx.x & 7;
    int c = blockIdx.x >> 3;
    int sbase = g * npg;
    int beg = colbase[blockIdx.x], end = colbase[blockIdx.x + 1];
    int q4 = (threadIdx.x & 3) * 4;      // feature quad 0/4/8/12
    int e = beg + (threadIdx.x >> 2);    // 128 edge slots
    for (; e + 128 < end; e += 256) {
        int v0 = ent[e], v1 = ent[e + 128];
        float4 r0 = *reinterpret_cast<const float4*>(dh1 + (size_t)(sbase + (v0 >> 11)) * F + q4);
        float4 r1 = *reinterpret_cast<const float4*>(dh1 + (size_t)(sbase + (v1 >> 11)) * F + q4);
        int a0 = (v0 & (CH - 1)) * 17 + q4;
        int a1 = (v1 & (CH - 1)) * 17 + q4;
        atomicAdd(&acc[a0 + 0], r0.x); atomicAdd(&acc[a0 + 1], r0.y);
        atomicAdd(&acc[a0 + 2], r0.z); atomicAdd(&acc[a0 + 3], r0.w);
        atomicAdd(&acc[a1 + 0], r1.x); atomicAdd(&acc[a1 + 1], r1.y);
        atomicAdd(&acc[a1 + 2], r1.z); atomicAdd(&acc[a1 + 3], r1.w);
    }
    for (; e < end; e += 128) {
        int v = ent[e];
        float4 r = *reinterpret_cast<const float4*>(dh1 + (size_t)(sbase + (v >> 11)) * F + q4);
        int a0 = (v & (CH - 1)) * 17 + q4;
        atomicAdd(&acc[a0 + 0], r.x); atomicAdd(&acc[a0 + 1], r.y);
        atomicAdd(&acc[a0 + 2], r.z); atomicAdd(&acc[a0 + 3], r.w);
    }
    __syncthreads();
    float* aggc = agg + (size_t)c * CH * F;
    for (int t = threadIdx.x; t < CH * F; t += 512) {
        int r = t >> 4, f = t & 15;
        atomicAdd(&aggc[t], acc[r * 17 + f]);   // coalesced; RMW merges in L2
    }
}

// ---- layer 2 pass B (flat epilogue): a = di*(agg+dh1_self); h2 = relu(a@W2+b2);
// dxw3 = di*(h2 . W3)

__global__ __launch_bounds__(256) void k_layer2b(const float* __restrict__ agg,
        const float* __restrict__ dh1, const float* __restrict__ dinv,
        const float* __restrict__ W2, const float* __restrict__ b2,
        const float* __restrict__ W3, float* __restrict__ dxw3, int n) {
    __shared__ float sW2[256];
    __shared__ float sW3[16];
    __shared__ float sb[16];
    sW2[threadIdx.x] = W2[threadIdx.x];
    if (threadIdx.x < 16) sW3[threadIdx.x] = W3[threadIdx.x];
    else if (threadIdx.x < 32) sb[threadIdx.x - 16] = b2[threadIdx.x - 16];
    __syncthreads();
    int i = blockIdx.x * 256 + threadIdx.x;
    if (i >= n) return;
    float di = dinv[i];
    const float* ag = agg + (size_t)i * F;
    const float* dh = dh1 + (size_t)i * F;
    float a[16];
#pragma unroll
    for (int q = 0; q < 16; ++q) a[q] = di * (ag[q] + dh[q]);
    float sum = 0.0f;
#pragma unroll
    for (int c = 0; c < 16; ++c) {
        float h = sb[c];
#pragma unroll
        for (int q = 0; q < 16; ++q) h += a[q] * sW2[q * 16 + c];
        sum += fmaxf(h, 0.0f) * sW3[c];
    }
    dxw3[i] = di * sum;
}

// ---- layer 3 (scalar gather) -> out ------------------------------------------

__global__ __launch_bounds__(512) void k_out(const int* __restrict__ ent,
        const int* __restrict__ colbase, const float* __restrict__ dinv,
        const float* __restrict__ dxw3, const float* __restrict__ b3,
        float* __restrict__ out, int n, int npg) {
    __shared__ float acc[CH];
    for (int t = threadIdx.x; t < CH; t += 512) acc[t] = 0.0f;
    __syncthreads();
    for (int g = 0; g < 8; ++g) {
        int sbase = g * npg;
        int beg = colbase[blockIdx.x * 8 + g], end = colbase[blockIdx.x * 8 + g + 1];
        int e = beg + threadIdx.x;
        for (; e + 512 < end; e += 1024) {
            int v0 = ent[e], v1 = ent[e + 512];
            float s0 = dxw3[sbase + (v0 >> 11)];
            float s1 = dxw3[sbase + (v1 >> 11)];
            atomicAdd(&acc[v0 & (CH - 1)], s0);
            atomicAdd(&acc[v1 & (CH - 1)], s1);
        }
        if (e < end) {
            int v = ent[e];
            atomicAdd(&acc[v & (CH - 1)], dxw3[sbase + (v >> 11)]);
        }
    }
    __syncthreads();
    for (int r = threadIdx.x; r < CH; r += 512) {
        int i = blockIdx.x * CH + r;
        if (i < n) out[i] = dinv[i] * (acc[r] + dxw3[i]) + b3[0];
    }
}

// ---- launch -------------------------------------------------------------------

extern "C" void kernel_launch(void* const* d_in, const int* in_sizes, int n_in,
                              void* d_out, int out_size, void* d_ws, size_t ws_size,
                              hipStream_t stream) {
    const float* x  = (const float*)d_in[0];
    const int*   ei = (const int*)d_in[1];
    const float* W1 = (const float*)d_in[2];
    const float* b1 = (const float*)d_in[3];
    const float* W2 = (const float*)d_in[4];
    const float* b2 = (const float*)d_in[5];
    const float* W3 = (const float*)d_in[6];
    const float* b3 = (const float*)d_in[7];

    const int n = in_sizes[0] / 2;            // [n,2]
    const int E = in_sizes[1] / 2;            // [2,E]
    const int* src = ei;
    const int* dst = ei + E;

    const int NC  = (n + CH - 1) / CH;        // 123 dst chunks
    const int B   = NC * 8;                   // 984 bins
    const int npg = (n + 7) / 8;              // 31250 src nodes per group

    char* w = (char*)d_ws;
    int*   ent     = (int*)w;                 w += (size_t)E * 4;              // 16MB
    int*   bcount  = (int*)w;                 w += (size_t)G * B * 4;          // ~1MB
    int*   colbase = (int*)w;                 w += (size_t)(B + 1) * 4;
    w = (char*)(((uintptr_t)w + 15) & ~(uintptr_t)15);
    float* dinv    = (float*)w;               w += (size_t)n * 4;              // 1MB
    float* dx      = (float*)w;               w += (size_t)n * 2 * 4;          // 2MB
    float* dh1     = (float*)w;               w += (size_t)n * F * 4;          // 16MB
    float* agg     = (float*)w;               w += (size_t)NC * CH * F * 4;    // 16.1MB
    float* dxw3    = (float*)w;               w += (size_t)n * 4;              // 1MB
    float* out     = (float*)d_out;

    const int chunk = (E + G - 1) / G;

    // binning by (dst chunk, src group)
    k_bcount<<<G, 1024, 0, stream>>>(src, dst, bcount, E, chunk, npg, B);
    k_scan  <<<1, 1024, 0, stream>>>(bcount, colbase, E, B);
    k_bfill <<<G, 1024, 0, stream>>>(src, dst, bcount, ent, E, chunk, npg, B);

    // degree + pre-scaled input
    k_prep<<<NC, 512, 0, stream>>>(ent, colbase, x, dinv, dx, n);

    // layer 1
    k_layer1<<<NC, 512, 0, stream>>>(ent, colbase, dinv, dx, W1, b1, dh1, n, npg);

    // layer 2: XCD-affinity gather into agg, then flat epilogue
    hipMemsetAsync(agg, 0, (size_t)NC * CH * F * 4, stream);
    k_layer2a<<<B, 512, 0, stream>>>(ent, colbase, dh1, agg, npg);
    k_layer2b<<<(n + 255) / 256, 256, 0, stream>>>(agg, dh1, dinv, W2, b2, W3, dxw3, n);

    // layer 3
    k_out<<<NC, 512, 0, stream>>>(ent, colbase, dinv, dxw3, b3, out, n, npg);
}